// Round 10
// baseline (56.771 us; speedup 1.0000x reference)
//
#include <hip/hip_runtime.h>
#include <math.h>

namespace {
constexpr int kDim = 2048;
constexpr int kH = 16;
constexpr int kD = 128;
constexpr int kS = 8192;
constexpr int kChunk = 16;             // keys per attn block (whole rows, all heads)
constexpr int kNC = kS / kChunk;       // 512 chunks
constexpr float kScale = 0.08838834764831843f; // 1/sqrt(128)
} // namespace

#define BATCH_FENCE() do { \
    asm volatile("s_waitcnt vmcnt(0)" ::: "memory"); \
    __builtin_amdgcn_sched_barrier(0); \
} while (0)

// One wave per output row. Rows [0,2048)=w_q, [2048,4096)=w_k, [4096,6144)=w_v.
__global__ __launch_bounds__(256) void qkv_gemv(
    const float* __restrict__ x, const float* __restrict__ wq,
    const float* __restrict__ wk, const float* __restrict__ wv,
    float* __restrict__ qkv)
{
    const int wid  = (blockIdx.x << 2) | ((int)threadIdx.x >> 6);
    const int lane = threadIdx.x & 63;
    const float* W;
    int r = wid;
    if (r < kDim)            { W = wq; }
    else if (r < 2 * kDim)   { W = wk; r -= kDim; }
    else                     { W = wv; r -= 2 * kDim; }
    const float4* wrow = reinterpret_cast<const float4*>(W + (size_t)r * kDim);
    const float4* x4   = reinterpret_cast<const float4*>(x);
    float4 wr[8], xv[8];
#pragma unroll
    for (int k = 0; k < 8; ++k) wr[k] = wrow[(k << 6) + lane];
#pragma unroll
    for (int k = 0; k < 8; ++k) xv[k] = x4[(k << 6) + lane];
    float acc = 0.f;
#pragma unroll
    for (int k = 0; k < 8; ++k)
        acc += wr[k].x * xv[k].x + wr[k].y * xv[k].y
             + wr[k].z * xv[k].z + wr[k].w * xv[k].w;
#pragma unroll
    for (int off = 32; off; off >>= 1) acc += __shfl_xor(acc, off, 64);
    if (lane == 0) qkv[wid] = acc;
}

// Fused attention, whole-row streaming: one block per 16-key chunk, ALL heads.
// K-phase: wave w owns rows 4w..4w+3; each row read as 8 contiguous 1KB
// wave-loads (full 8KB row), batch-fenced so 8 loads stay in flight.
// V-phase: wave w owns column groups g2 = {2w, 2w+1} across all 16 rows;
// per (row,g2) a contiguous 1KB wave-load. Softmax weights via LDS broadcast.
// Waves own disjoint heads -> no cross-wave reduction; single barrier.
__global__ __launch_bounds__(256) void attn_fused(
    const float* __restrict__ k_cache, const float* __restrict__ v_cache,
    const float* __restrict__ qkv, const int* __restrict__ pos_p,
    float* __restrict__ part, float2* __restrict__ ml)
{
    const int chunk = blockIdx.x;
    const int wave  = threadIdx.x >> 6;
    const int lane  = threadIdx.x & 63;
    const int half  = lane >> 5;
    const int l32   = lane & 31;
    const int pos   = pos_p[0];
    const int kb0   = chunk * kChunk;

    __shared__ float s_lds[kH][kChunk];   // scores, then e = exp(s - m_h)

    const float4* kc4   = reinterpret_cast<const float4*>(k_cache);
    const float4* vc4   = reinterpret_cast<const float4*>(v_cache);
    const float4* qkv4  = reinterpret_cast<const float4*>(qkv);
    const float4* knew4 = qkv4 + 512;     // qkv + kDim
    const float4* vnew4 = qkv4 + 1024;    // qkv + 2*kDim

    // q fragment per lane: for column group g, lane covers head 2g+half,
    // dim quad l32. qreg[g] = q[(2g+half)*128 + l32*4 ..+4]
    float4 qreg[8];
#pragma unroll
    for (int g = 0; g < 8; ++g)
        qreg[g] = qkv4[(2 * g + half) * 32 + l32];

    // ---- K-phase: 4 full rows, 8 batched contiguous loads each ----
#pragma unroll
    for (int i = 0; i < 4; ++i) {
        const int rl  = wave * 4 + i;          // row-local 0..15
        const int row = kb0 + rl;
        const float4* kr = (row == pos) ? knew4 : (kc4 + (size_t)row * 512);
        float4 kv[8];
#pragma unroll
        for (int g = 0; g < 8; ++g) kv[g] = kr[g * 64 + lane];
        BATCH_FENCE();
        float p[8];
#pragma unroll
        for (int g = 0; g < 8; ++g)
            p[g] = kv[g].x * qreg[g].x + kv[g].y * qreg[g].y
                 + kv[g].z * qreg[g].z + kv[g].w * qreg[g].w;
#pragma unroll
        for (int mask = 1; mask <= 16; mask <<= 1) {
#pragma unroll
            for (int g = 0; g < 8; ++g) p[g] += __shfl_xor(p[g], mask, 32);
        }
        if (l32 == 0) {
            const bool valid = (row <= pos);
#pragma unroll
            for (int g = 0; g < 8; ++g)
                s_lds[2 * g + half][rl] = valid ? p[g] * kScale : -INFINITY;
        }
    }

    // ---- Issue first V batch (rows 0..3, own g2 pair) BEFORE the barrier ----
    const int g2a = 2 * wave;                  // own column groups: g2a, g2a+1
    float4 vv[8];
#pragma unroll
    for (int j = 0; j < 8; ++j) {
        const int row = kb0 + (j >> 1);
        const int g2  = g2a + (j & 1);
        const float4* vr = (row == pos) ? vnew4 : (vc4 + (size_t)row * 512);
        vv[j] = vr[g2 * 64 + lane];
    }

    __syncthreads();

    // ---- Softmax for OWN heads (2 per lane-half): wave-parallel over rows ----
#pragma unroll
    for (int gi = 0; gi < 2; ++gi) {
        const int h = 2 * (g2a + gi) + half;
        float s_r = (l32 < kChunk) ? s_lds[h][l32] : -INFINITY;
        float mh = s_r;
#pragma unroll
        for (int mask = 1; mask <= 16; mask <<= 1)
            mh = fmaxf(mh, __shfl_xor(mh, mask, 32));
        const float eh = (s_r > -INFINITY) ? __expf(s_r - mh) : 0.f;
        float lh = eh;
#pragma unroll
        for (int mask = 1; mask <= 16; mask <<= 1)
            lh += __shfl_xor(lh, mask, 32);
        if (l32 < kChunk) s_lds[h][l32] = eh;
        if (l32 == 0) ml[h * kNC + chunk] = make_float2(mh, lh);
    }

    // ---- V-phase: 4 batches of 8 contiguous 1KB loads, weighted accumulate ----
    float4 acc0 = make_float4(0.f, 0.f, 0.f, 0.f);
    float4 acc1 = make_float4(0.f, 0.f, 0.f, 0.f);
#pragma unroll
    for (int b = 0; b < 4; ++b) {
        BATCH_FENCE();
        float4 cur[8];
#pragma unroll
        for (int j = 0; j < 8; ++j) cur[j] = vv[j];
        if (b < 3) {
#pragma unroll
            for (int j = 0; j < 8; ++j) {
                const int row = kb0 + 4 * (b + 1) + (j >> 1);
                const int g2  = g2a + (j & 1);
                const float4* vr = (row == pos) ? vnew4 : (vc4 + (size_t)row * 512);
                vv[j] = vr[g2 * 64 + lane];
            }
        }
#pragma unroll
        for (int j = 0; j < 8; ++j) {
            const int rl = 4 * b + (j >> 1);
            const int h  = 2 * (g2a + (j & 1)) + half;
            const float e = s_lds[h][rl];
            if ((j & 1) == 0) {
                acc0.x += e * cur[j].x; acc0.y += e * cur[j].y;
                acc0.z += e * cur[j].z; acc0.w += e * cur[j].w;
            } else {
                acc1.x += e * cur[j].x; acc1.y += e * cur[j].y;
                acc1.z += e * cur[j].z; acc1.w += e * cur[j].w;
            }
        }
    }

    // ---- Write partials: head (2*(g2a+gi)+half), dims l32*4..+4 ----
    float4* part4 = reinterpret_cast<float4*>(part);
    const int h0 = 2 * g2a + half;
    const int h1 = 2 * (g2a + 1) + half;
    part4[((size_t)h0 * kNC + chunk) * 32 + l32] = acc0;
    part4[((size_t)h1 * kNC + chunk) * 32 + l32] = acc1;
}

// Combine: one block (128 thr) per head over 512 chunk-partials.
__global__ __launch_bounds__(128) void combine_partials(
    const float* __restrict__ part, const float2* __restrict__ ml,
    float* __restrict__ o_out)
{
    const int h    = blockIdx.x;
    const int t    = threadIdx.x;
    const int wave = t >> 6;
    const int lane = t & 63;
    __shared__ float wred[2], wsum[2], f_lds[kNC];

    float2 mlv[4];
    float mloc = -INFINITY;
#pragma unroll
    for (int k = 0; k < 4; ++k) {
        mlv[k] = ml[h * kNC + t + 128 * k];
        mloc = fmaxf(mloc, mlv[k].x);
    }
#pragma unroll
    for (int m = 32; m; m >>= 1) mloc = fmaxf(mloc, __shfl_xor(mloc, m, 64));
    if (lane == 0) wred[wave] = mloc;
    __syncthreads();
    const float Mg = fmaxf(wred[0], wred[1]);

    float lf = 0.f;
#pragma unroll
    for (int k = 0; k < 4; ++k) {
        const float f = (mlv[k].y > 0.f) ? __expf(mlv[k].x - Mg) : 0.f;
        f_lds[t + 128 * k] = f;
        lf += mlv[k].y * f;
    }
#pragma unroll
    for (int m = 32; m; m >>= 1) lf += __shfl_xor(lf, m, 64);
    if (lane == 0) wsum[wave] = lf;
    __syncthreads();
    const float Lg = wsum[0] + wsum[1];

    float O = 0.f;
    const float* base = part + (size_t)h * kNC * kD + t;
#pragma unroll 8
    for (int c = 0; c < kNC; ++c)
        O += f_lds[c] * base[(size_t)c * kD];
    o_out[h * kD + t] = O / Lg;
}

// Output projection GEMV: one wave per output row.
__global__ __launch_bounds__(256) void out_gemv(
    const float* __restrict__ o, const float* __restrict__ wo,
    float* __restrict__ out)
{
    const int wid  = (blockIdx.x << 2) | ((int)threadIdx.x >> 6);
    const int lane = threadIdx.x & 63;
    const float4* wrow = reinterpret_cast<const float4*>(wo + (size_t)wid * kDim);
    const float4* x4   = reinterpret_cast<const float4*>(o);
    float4 wr[8], xv[8];
#pragma unroll
    for (int k = 0; k < 8; ++k) wr[k] = wrow[(k << 6) + lane];
#pragma unroll
    for (int k = 0; k < 8; ++k) xv[k] = x4[(k << 6) + lane];
    float acc = 0.f;
#pragma unroll
    for (int k = 0; k < 8; ++k)
        acc += wr[k].x * xv[k].x + wr[k].y * xv[k].y
             + wr[k].z * xv[k].z + wr[k].w * xv[k].w;
#pragma unroll
    for (int off = 32; off; off >>= 1) acc += __shfl_xor(acc, off, 64);
    if (lane == 0) out[wid] = acc;
}

extern "C" void kernel_launch(void* const* d_in, const int* in_sizes, int n_in,
                              void* d_out, int out_size, void* d_ws, size_t ws_size,
                              hipStream_t stream)
{
    const float* x       = (const float*)d_in[0];
    const float* k_cache = (const float*)d_in[1];
    const float* v_cache = (const float*)d_in[2];
    const float* wq      = (const float*)d_in[3];
    const float* wk      = (const float*)d_in[4];
    const float* wv      = (const float*)d_in[5];
    const float* wo      = (const float*)d_in[6];
    const int*   pos     = (const int*)d_in[7];
    float* out = (float*)d_out;

    float*  ws    = (float*)d_ws;
    float*  qkv   = ws;                                  // 3*2048
    float*  part  = qkv + 3 * kDim;                      // 16*512*128 = 1M floats
    float2* ml    = (float2*)(part + (size_t)kH * kNC * kD); // 16*512 float2
    float*  o_out = (float*)(ml + kH * kNC);             // 2048

    qkv_gemv<<<3 * kDim / 4, 256, 0, stream>>>(x, wq, wk, wv, qkv);
    attn_fused<<<kNC, 256, 0, stream>>>(k_cache, v_cache, qkv, pos, part, ml);
    combine_partials<<<kH, 128, 0, stream>>>(part, ml, o_out);
    out_gemv<<<kDim / 4, 256, 0, stream>>>(o_out, wo, out);
}

// Round 11
// 46.628 us; speedup vs baseline: 1.2175x; 1.2175x over previous
//
#include <hip/hip_runtime.h>
#include <math.h>

namespace {
constexpr int kDim = 2048;
constexpr int kH = 16;
constexpr int kD = 128;
constexpr int kS = 8192;
constexpr int kChunk = 128;            // keys per attn block
constexpr int kNChunk = kS / kChunk;   // 64
constexpr float kScale = 0.08838834764831843f; // 1/sqrt(128)
} // namespace

// One wave per output row. Rows [0,2048)=w_q, [2048,4096)=w_k, [4096,6144)=w_v.
__global__ __launch_bounds__(256) void qkv_gemv(
    const float* __restrict__ x, const float* __restrict__ wq,
    const float* __restrict__ wk, const float* __restrict__ wv,
    float* __restrict__ qkv)
{
    const int wid  = (blockIdx.x << 2) | ((int)threadIdx.x >> 6);
    const int lane = threadIdx.x & 63;
    const float* W;
    int r = wid;
    if (r < kDim)            { W = wq; }
    else if (r < 2 * kDim)   { W = wk; r -= kDim; }
    else                     { W = wv; r -= 2 * kDim; }
    const float4* wrow = reinterpret_cast<const float4*>(W + (size_t)r * kDim);
    const float4* x4   = reinterpret_cast<const float4*>(x);
    float4 wr[8], xv[8];
#pragma unroll
    for (int k = 0; k < 8; ++k) wr[k] = wrow[(k << 6) + lane];
#pragma unroll
    for (int k = 0; k < 8; ++k) xv[k] = x4[(k << 6) + lane];
    float acc = 0.f;
#pragma unroll
    for (int k = 0; k < 8; ++k)
        acc += wr[k].x * xv[k].x + wr[k].y * xv[k].y
             + wr[k].z * xv[k].z + wr[k].w * xv[k].w;
#pragma unroll
    for (int off = 32; off; off >>= 1) acc += __shfl_xor(acc, off, 64);
    if (lane == 0) qkv[wid] = acc;
}

// Fused attention (R5 structure): one block per (head, 128-key chunk).
// Phase 1: scores via kq/q lane map. Phase 2: chunk max + exp (LDS).
// Phase 3: streaming PV via half-wave map.
// SINGLE CHANGE vs R5: the first 8-deep V batch is issued BEFORE Phase 2,
// so each wave keeps 8 loads in flight through the softmax/barrier window.
__global__ __launch_bounds__(256) void attn_fused(
    const float* __restrict__ k_cache, const float* __restrict__ v_cache,
    const float* __restrict__ qkv, const int* __restrict__ pos_p,
    float* __restrict__ part)
{
    const int h     = blockIdx.x >> 6;
    const int chunk = blockIdx.x & (kNChunk - 1);
    const int wave  = threadIdx.x >> 6;
    const int lane  = threadIdx.x & 63;
    const int half  = lane >> 5;
    const int l32   = lane & 31;
    const int t     = threadIdx.x;
    const int pos   = pos_p[0];
    const int s0    = chunk * kChunk;

    __shared__ float  s_lds[kChunk];     // scores, then e = exp(s - M)
    __shared__ float  wred[4];
    __shared__ float4 sacc[4][32];

    const float* knew = qkv + kDim + h * kD;
    const float* vnew = qkv + 2 * kDim + h * kD;

    // ---- Phase 1: scores (16 keys per wave per g; 4 lanes x 32 dims per key) ----
    {
        const int kq = lane >> 2;
        const int q  = lane & 3;
        const float4* q4p = reinterpret_cast<const float4*>(qkv + h * kD + q * 32);
        float4 qv[8];
#pragma unroll
        for (int i = 0; i < 8; ++i) qv[i] = q4p[i];
#pragma unroll
        for (int g = 0; g < 2; ++g) {
            const int key = s0 + wave * 32 + g * 16 + kq;
            const float4* kp = reinterpret_cast<const float4*>(
                ((key == pos) ? knew : (k_cache + (size_t)key * kDim + h * kD)) + q * 32);
            float4 kv[8];
#pragma unroll
            for (int i = 0; i < 8; ++i) kv[i] = kp[i];
            float s = 0.f;
#pragma unroll
            for (int i = 0; i < 8; ++i)
                s += kv[i].x * qv[i].x + kv[i].y * qv[i].y
                   + kv[i].z * qv[i].z + kv[i].w * qv[i].w;
            s += __shfl_xor(s, 1, 64);
            s += __shfl_xor(s, 2, 64);
            if (q == 0)
                s_lds[wave * 32 + g * 16 + kq] = (key <= pos) ? s * kScale : -INFINITY;
        }
    }

    // ---- V prefetch (g=0 batch): no dependency on scores; these 8 loads
    //      stay outstanding through the whole Phase-2 softmax window. ----
    float4 vpre[8];
#pragma unroll
    for (int it = 0; it < 8; ++it) {
        const int key = s0 + wave * 32 + 2 * it + half;
        const float* vp = (key == pos) ? vnew
                                       : (v_cache + (size_t)key * kDim + h * kD);
        vpre[it] = reinterpret_cast<const float4*>(vp)[l32];
    }

    __syncthreads();

    // ---- Phase 2: chunk max + exp ----
    const float sc_t = (t < kChunk) ? s_lds[t] : -INFINITY;
    {
        float mx = sc_t;
#pragma unroll
        for (int m = 32; m; m >>= 1) mx = fmaxf(mx, __shfl_xor(mx, m, 64));
        if (lane == 0) wred[wave] = mx;
    }
    __syncthreads();
    const float M = fmaxf(fmaxf(wred[0], wred[1]), fmaxf(wred[2], wred[3]));
    if (t < kChunk) s_lds[t] = (M > -INFINITY) ? __expf(sc_t - M) : 0.f;
    __syncthreads();

    // ---- Phase 3: PV (batch 0 = prefetched; batch 1 loads now) ----
    {
        float4 acc = make_float4(0.f, 0.f, 0.f, 0.f);
        float  ev[8];
        // batch 1 loads issue first so they fly while batch 0 is consumed
        float4 v1[8];
#pragma unroll
        for (int it = 0; it < 8; ++it) {
            const int key = s0 + wave * 32 + 16 + 2 * it + half;
            const float* vp = (key == pos) ? vnew
                                           : (v_cache + (size_t)key * kDim + h * kD);
            v1[it] = reinterpret_cast<const float4*>(vp)[l32];
        }
        // consume prefetched batch 0
#pragma unroll
        for (int it = 0; it < 8; ++it)
            ev[it] = s_lds[wave * 32 + 2 * it + half];
#pragma unroll
        for (int it = 0; it < 8; ++it) {
            acc.x += ev[it] * vpre[it].x;
            acc.y += ev[it] * vpre[it].y;
            acc.z += ev[it] * vpre[it].z;
            acc.w += ev[it] * vpre[it].w;
        }
        // consume batch 1
#pragma unroll
        for (int it = 0; it < 8; ++it)
            ev[it] = s_lds[wave * 32 + 16 + 2 * it + half];
#pragma unroll
        for (int it = 0; it < 8; ++it) {
            acc.x += ev[it] * v1[it].x;
            acc.y += ev[it] * v1[it].y;
            acc.z += ev[it] * v1[it].z;
            acc.w += ev[it] * v1[it].w;
        }
        acc.x += __shfl_xor(acc.x, 32, 64);
        acc.y += __shfl_xor(acc.y, 32, 64);
        acc.z += __shfl_xor(acc.z, 32, 64);
        acc.w += __shfl_xor(acc.w, 32, 64);
        if (half == 0) sacc[wave][l32] = acc;
    }
    __syncthreads();

    if (wave == 0 && lane < 32) {
        float4 A = sacc[0][l32];
        const float4 B = sacc[1][l32], C = sacc[2][l32], D = sacc[3][l32];
        A.x += B.x + C.x + D.x;
        A.y += B.y + C.y + D.y;
        A.z += B.z + C.z + D.z;
        A.w += B.w + C.w + D.w;
        float le = s_lds[l32] + s_lds[l32 + 32] + s_lds[l32 + 64] + s_lds[l32 + 96];
#pragma unroll
        for (int m = 16; m; m >>= 1) le += __shfl_xor(le, m, 64);
        float* pp = part + (size_t)(h * kNChunk + chunk) * (kD + 2);
        reinterpret_cast<float4*>(pp)[l32] = A;
        if (l32 == 0) { pp[kD] = M; pp[kD + 1] = le; }
    }
}

// Combine: one block per head. Per-chunk factors staged in LDS, then 64
// independent partial loads per thread.
__global__ __launch_bounds__(128) void combine_partials(
    const float* __restrict__ part, float* __restrict__ o_out)
{
    const int h = blockIdx.x;
    const int t = threadIdx.x;
    __shared__ float f_lds[kNChunk];
    __shared__ float Lg;

    float mc = -INFINITY, lc = 0.f;
    if (t < kNChunk) {
        const float* pp = part + (size_t)(h * kNChunk + t) * (kD + 2);
        mc = pp[kD];
        lc = pp[kD + 1];
    }
    if (t < 64) {
        float Mg = mc;
#pragma unroll
        for (int m = 32; m; m >>= 1) Mg = fmaxf(Mg, __shfl_xor(Mg, m, 64));
        const float f = (lc > 0.f) ? __expf(mc - Mg) : 0.f;
        f_lds[t] = f;
        float lf = lc * f;
#pragma unroll
        for (int m = 32; m; m >>= 1) lf += __shfl_xor(lf, m, 64);
        if (t == 0) Lg = lf;
    }
    __syncthreads();

    float O = 0.f;
    const float* base = part + (size_t)h * kNChunk * (kD + 2) + t;
#pragma unroll 8
    for (int c = 0; c < kNChunk; ++c)
        O += base[(size_t)c * (kD + 2)] * f_lds[c];
    o_out[h * kD + t] = O / Lg;
}

// Output projection GEMV: one wave per output row.
__global__ __launch_bounds__(256) void out_gemv(
    const float* __restrict__ o, const float* __restrict__ wo,
    float* __restrict__ out)
{
    const int wid  = (blockIdx.x << 2) | ((int)threadIdx.x >> 6);
    const int lane = threadIdx.x & 63;
    const float4* wrow = reinterpret_cast<const float4*>(wo + (size_t)wid * kDim);
    const float4* x4   = reinterpret_cast<const float4*>(o);
    float4 wr[8], xv[8];
#pragma unroll
    for (int k = 0; k < 8; ++k) wr[k] = wrow[(k << 6) + lane];
#pragma unroll
    for (int k = 0; k < 8; ++k) xv[k] = x4[(k << 6) + lane];
    float acc = 0.f;
#pragma unroll
    for (int k = 0; k < 8; ++k)
        acc += wr[k].x * xv[k].x + wr[k].y * xv[k].y
             + wr[k].z * xv[k].z + wr[k].w * xv[k].w;
#pragma unroll
    for (int off = 32; off; off >>= 1) acc += __shfl_xor(acc, off, 64);
    if (lane == 0) out[wid] = acc;
}

extern "C" void kernel_launch(void* const* d_in, const int* in_sizes, int n_in,
                              void* d_out, int out_size, void* d_ws, size_t ws_size,
                              hipStream_t stream)
{
    const float* x       = (const float*)d_in[0];
    const float* k_cache = (const float*)d_in[1];
    const float* v_cache = (const float*)d_in[2];
    const float* wq      = (const float*)d_in[3];
    const float* wk      = (const float*)d_in[4];
    const float* wv      = (const float*)d_in[5];
    const float* wo      = (const float*)d_in[6];
    const int*   pos     = (const int*)d_in[7];
    float* out = (float*)d_out;

    float* ws    = (float*)d_ws;
    float* qkv   = ws;                                   // 3*2048
    float* part  = qkv + 3 * kDim;                       // 16*64*130
    float* o_out = part + kH * kNChunk * (kD + 2);       // 2048

    qkv_gemv<<<3 * kDim / 4, 256, 0, stream>>>(x, wq, wk, wv, qkv);
    attn_fused<<<kH * kNChunk, 256, 0, stream>>>(k_cache, v_cache, qkv, pos, part);
    combine_partials<<<kH, 128, 0, stream>>>(part, o_out);
    out_gemv<<<kDim / 4, 256, 0, stream>>>(o_out, wo, out);
}

// Round 12
// 46.199 us; speedup vs baseline: 1.2288x; 1.0093x over previous
//
#include <hip/hip_runtime.h>
#include <math.h>

namespace {
constexpr int kDim = 2048;
constexpr int kH = 16;
constexpr int kD = 128;
constexpr int kS = 8192;
constexpr int kChunk = 128;            // keys per attn block
constexpr int kNChunk = kS / kChunk;   // 64
constexpr float kScale = 0.08838834764831843f; // 1/sqrt(128)
} // namespace

// One wave per output row. Rows [0,2048)=w_q, [2048,4096)=w_k, [4096,6144)=w_v.
__global__ __launch_bounds__(256) void qkv_gemv(
    const float* __restrict__ x, const float* __restrict__ wq,
    const float* __restrict__ wk, const float* __restrict__ wv,
    float* __restrict__ qkv)
{
    const int wid  = (blockIdx.x << 2) | ((int)threadIdx.x >> 6);
    const int lane = threadIdx.x & 63;
    const float* W;
    int r = wid;
    if (r < kDim)            { W = wq; }
    else if (r < 2 * kDim)   { W = wk; r -= kDim; }
    else                     { W = wv; r -= 2 * kDim; }
    const float4* wrow = reinterpret_cast<const float4*>(W + (size_t)r * kDim);
    const float4* x4   = reinterpret_cast<const float4*>(x);
    float4 wr[8], xv[8];
#pragma unroll
    for (int k = 0; k < 8; ++k) wr[k] = wrow[(k << 6) + lane];
#pragma unroll
    for (int k = 0; k < 8; ++k) xv[k] = x4[(k << 6) + lane];
    float acc = 0.f;
#pragma unroll
    for (int k = 0; k < 8; ++k)
        acc += wr[k].x * xv[k].x + wr[k].y * xv[k].y
             + wr[k].z * xv[k].z + wr[k].w * xv[k].w;
#pragma unroll
    for (int off = 32; off; off >>= 1) acc += __shfl_xor(acc, off, 64);
    if (lane == 0) qkv[wid] = acc;
}

// Fused attention: one block per (head, 128-key chunk).
// Phase 1: scores -> LDS. Phase 2: chunk max + exp. Phase 3: streaming PV.
// Partials {o[128], M, l} go to ws; combine happens in a separate tiny kernel.
__global__ __launch_bounds__(256) void attn_fused(
    const float* __restrict__ k_cache, const float* __restrict__ v_cache,
    const float* __restrict__ qkv, const int* __restrict__ pos_p,
    float* __restrict__ part)
{
    const int h     = blockIdx.x >> 6;
    const int chunk = blockIdx.x & (kNChunk - 1);
    const int wave  = threadIdx.x >> 6;
    const int lane  = threadIdx.x & 63;
    const int t     = threadIdx.x;
    const int pos   = pos_p[0];
    const int s0    = chunk * kChunk;

    __shared__ float  s_lds[kChunk];     // scores, then e = exp(s - M)
    __shared__ float  wred[4];
    __shared__ float4 sacc[4][32];

    const float* knew = qkv + kDim + h * kD;
    const float* vnew = qkv + 2 * kDim + h * kD;

    // ---- Phase 1: scores (16 keys per wave per g; 4 lanes x 32 dims per key) ----
    {
        const int kq = lane >> 2;
        const int q  = lane & 3;
        const float4* q4p = reinterpret_cast<const float4*>(qkv + h * kD + q * 32);
        float4 qv[8];
#pragma unroll
        for (int i = 0; i < 8; ++i) qv[i] = q4p[i];
#pragma unroll
        for (int g = 0; g < 2; ++g) {
            const int key = s0 + wave * 32 + g * 16 + kq;
            const float4* kp = reinterpret_cast<const float4*>(
                ((key == pos) ? knew : (k_cache + (size_t)key * kDim + h * kD)) + q * 32);
            float4 kv[8];
#pragma unroll
            for (int i = 0; i < 8; ++i) kv[i] = kp[i];
            float s = 0.f;
#pragma unroll
            for (int i = 0; i < 8; ++i)
                s += kv[i].x * qv[i].x + kv[i].y * qv[i].y
                   + kv[i].z * qv[i].z + kv[i].w * qv[i].w;
            s += __shfl_xor(s, 1, 64);
            s += __shfl_xor(s, 2, 64);
            if (q == 0)
                s_lds[wave * 32 + g * 16 + kq] = (key <= pos) ? s * kScale : -INFINITY;
        }
    }
    __syncthreads();

    // ---- Phase 2: chunk max + exp ----
    const float sc_t = (t < kChunk) ? s_lds[t] : -INFINITY;
    {
        float mx = sc_t;
#pragma unroll
        for (int m = 32; m; m >>= 1) mx = fmaxf(mx, __shfl_xor(mx, m, 64));
        if (lane == 0) wred[wave] = mx;
    }
    __syncthreads();
    const float M = fmaxf(fmaxf(wred[0], wred[1]), fmaxf(wred[2], wred[3]));
    if (t < kChunk) s_lds[t] = (M > -INFINITY) ? __expf(sc_t - M) : 0.f;
    __syncthreads();

    // ---- Phase 3: PV (2 keys per instr via wave halves; 8 loads in flight) ----
    {
        const int half = lane >> 5;
        const int l32  = lane & 31;
        float4 v[8];
        float  ev[8];
        float4 acc = make_float4(0.f, 0.f, 0.f, 0.f);
#pragma unroll
        for (int g = 0; g < 2; ++g) {
#pragma unroll
            for (int it = 0; it < 8; ++it) {
                const int key = s0 + wave * 32 + g * 16 + 2 * it + half;
                const float* vp = (key == pos) ? vnew
                                               : (v_cache + (size_t)key * kDim + h * kD);
                v[it] = reinterpret_cast<const float4*>(vp)[l32];
            }
#pragma unroll
            for (int it = 0; it < 8; ++it)
                ev[it] = s_lds[wave * 32 + g * 16 + 2 * it + half];
#pragma unroll
            for (int it = 0; it < 8; ++it) {
                acc.x += ev[it] * v[it].x;
                acc.y += ev[it] * v[it].y;
                acc.z += ev[it] * v[it].z;
                acc.w += ev[it] * v[it].w;
            }
        }
        acc.x += __shfl_xor(acc.x, 32, 64);
        acc.y += __shfl_xor(acc.y, 32, 64);
        acc.z += __shfl_xor(acc.z, 32, 64);
        acc.w += __shfl_xor(acc.w, 32, 64);
        if (half == 0) sacc[wave][l32] = acc;
    }
    __syncthreads();

    if (wave == 0 && lane < 32) {
        const int l32 = lane;
        float4 A = sacc[0][l32];
        const float4 B = sacc[1][l32], C = sacc[2][l32], D = sacc[3][l32];
        A.x += B.x + C.x + D.x;
        A.y += B.y + C.y + D.y;
        A.z += B.z + C.z + D.z;
        A.w += B.w + C.w + D.w;
        float le = s_lds[l32] + s_lds[l32 + 32] + s_lds[l32 + 64] + s_lds[l32 + 96];
#pragma unroll
        for (int m = 16; m; m >>= 1) le += __shfl_xor(le, m, 64);
        float* pp = part + (size_t)(h * kNChunk + chunk) * (kD + 2);
        reinterpret_cast<float4*>(pp)[l32] = A;
        if (l32 == 0) { pp[kD] = M; pp[kD + 1] = le; }
    }
}

// Combine: one block per head. Per-chunk factors staged in LDS, then 64
// independent partial loads per thread.
__global__ __launch_bounds__(128) void combine_partials(
    const float* __restrict__ part, float* __restrict__ o_out)
{
    const int h = blockIdx.x;
    const int t = threadIdx.x;
    __shared__ float f_lds[kNChunk];
    __shared__ float Lg;

    float mc = -INFINITY, lc = 0.f;
    if (t < kNChunk) {
        const float* pp = part + (size_t)(h * kNChunk + t) * (kD + 2);
        mc = pp[kD];
        lc = pp[kD + 1];
    }
    if (t < 64) {
        float Mg = mc;
#pragma unroll
        for (int m = 32; m; m >>= 1) Mg = fmaxf(Mg, __shfl_xor(Mg, m, 64));
        const float f = (lc > 0.f) ? __expf(mc - Mg) : 0.f;
        f_lds[t] = f;
        float lf = lc * f;
#pragma unroll
        for (int m = 32; m; m >>= 1) lf += __shfl_xor(lf, m, 64);
        if (t == 0) Lg = lf;
    }
    __syncthreads();

    float O = 0.f;
    const float* base = part + (size_t)h * kNChunk * (kD + 2) + t;
#pragma unroll 8
    for (int c = 0; c < kNChunk; ++c)
        O += base[(size_t)c * (kD + 2)] * f_lds[c];
    o_out[h * kD + t] = O / Lg;
}

// Output projection GEMV: one wave per output row.
__global__ __launch_bounds__(256) void out_gemv(
    const float* __restrict__ o, const float* __restrict__ wo,
    float* __restrict__ out)
{
    const int wid  = (blockIdx.x << 2) | ((int)threadIdx.x >> 6);
    const int lane = threadIdx.x & 63;
    const float4* wrow = reinterpret_cast<const float4*>(wo + (size_t)wid * kDim);
    const float4* x4   = reinterpret_cast<const float4*>(o);
    float4 wr[8], xv[8];
#pragma unroll
    for (int k = 0; k < 8; ++k) wr[k] = wrow[(k << 6) + lane];
#pragma unroll
    for (int k = 0; k < 8; ++k) xv[k] = x4[(k << 6) + lane];
    float acc = 0.f;
#pragma unroll
    for (int k = 0; k < 8; ++k)
        acc += wr[k].x * xv[k].x + wr[k].y * xv[k].y
             + wr[k].z * xv[k].z + wr[k].w * xv[k].w;
#pragma unroll
    for (int off = 32; off; off >>= 1) acc += __shfl_xor(acc, off, 64);
    if (lane == 0) out[wid] = acc;
}

extern "C" void kernel_launch(void* const* d_in, const int* in_sizes, int n_in,
                              void* d_out, int out_size, void* d_ws, size_t ws_size,
                              hipStream_t stream)
{
    const float* x       = (const float*)d_in[0];
    const float* k_cache = (const float*)d_in[1];
    const float* v_cache = (const float*)d_in[2];
    const float* wq      = (const float*)d_in[3];
    const float* wk      = (const float*)d_in[4];
    const float* wv      = (const float*)d_in[5];
    const float* wo      = (const float*)d_in[6];
    const int*   pos     = (const int*)d_in[7];
    float* out = (float*)d_out;

    float* ws    = (float*)d_ws;
    float* qkv   = ws;                                   // 3*2048
    float* part  = qkv + 3 * kDim;                       // 16*64*130
    float* o_out = part + kH * kNChunk * (kD + 2);       // 2048

    qkv_gemv<<<3 * kDim / 4, 256, 0, stream>>>(x, wq, wk, wv, qkv);
    attn_fused<<<kH * kNChunk, 256, 0, stream>>>(k_cache, v_cache, qkv, pos, part);
    combine_partials<<<kH, 128, 0, stream>>>(part, o_out);
    out_gemv<<<kDim / 4, 256, 0, stream>>>(o_out, wo, out);
}